// Round 5
// baseline (111.847 us; speedup 1.0000x reference)
//
#include <hip/hip_runtime.h>

#define NM 8     // marginals
#define NN 128   // nodes
#define NI 127   // intervals
#define SPAD 129 // padded row stride for solve scratch

#define GRID 1024
#define PT 16    // float4 per thread, all loaded up-front for MLP

// Thomas-algorithm elimination multipliers for the fixed interior [1,4,1] system.
struct CpTab { float v[NN]; };
constexpr CpTab make_cp() {
    CpTab t{};
    t.v[0] = 0.0f;
    double p = 0.0;
    for (int i = 1; i <= 126; ++i) { p = 1.0 / (4.0 - p); t.v[i] = (float)p; }
    t.v[127] = 0.0f;
    return t;
}
__constant__ CpTab CP = make_cp();

// ---------- Kernel A: coefficient solve, ONCE (1 block). Also zeroes out[0]. ----------
__global__ __launch_bounds__(256)
void spline_coeff_kernel(const float* __restrict__ nodal,
                         float2* __restrict__ gAB,
                         float2* __restrict__ gCD,
                         float* __restrict__ out) {
    __shared__ float yv[NM * NN];
    __shared__ float sc[NM * SPAD];
    const int tid = threadIdx.x;
    const float h      = 8.0f / 127.0f;
    const float inv_h  = 127.0f / 8.0f;
    const float inv_h2 = inv_h * inv_h;

    if (tid == 0) out[0] = 0.0f;   // eval kernel accumulates via atomicAdd

    for (int t = tid; t < NM * NN; t += 256) yv[t] = nodal[t];
    __syncthreads();
    for (int t = tid; t < NM * 126; t += 256) {
        int f = t / 126, i = t - f * 126 + 1;
        sc[f * SPAD + i] = 3.0f * (yv[f * NN + i - 1] - 2.0f * yv[f * NN + i]
                                   + yv[f * NN + i + 1]) * inv_h2;
    }
    __syncthreads();
    if (tid < NM) {               // serial Thomas sweeps, one marginal per lane
        const int f = tid;
        float prev = 0.0f;
        #pragma unroll
        for (int i = 1; i <= 126; ++i) {
            prev = (sc[f * SPAD + i] - prev) * CP.v[i];
            sc[f * SPAD + i] = prev;
        }
        float cn = 0.0f;
        #pragma unroll
        for (int i = 126; i >= 1; --i) {
            cn = sc[f * SPAD + i] - CP.v[i] * cn;
            sc[f * SPAD + i] = cn;
        }
        sc[f * SPAD + 0]   = 0.0f;
        sc[f * SPAD + 127] = 0.0f;
    }
    __syncthreads();
    for (int t = tid; t < NM * NI; t += 256) {
        int f = t / NI, i = t - f * NI;
        float ci  = sc[f * SPAD + i];
        float ci1 = sc[f * SPAD + i + 1];
        float a = yv[f * NN + i];
        float b = (yv[f * NN + i + 1] - a) * inv_h - h * (2.0f * ci + ci1) * (1.0f / 3.0f);
        float d = (ci1 - ci) * inv_h * (1.0f / 3.0f);
        gAB[t] = make_float2(a, b);
        gCD[t] = make_float2(ci, d);
    }
}

__device__ __forceinline__ float eval1(float xv,
                                       const float2* __restrict__ tAB,
                                       const float2* __restrict__ tCD) {
    // reference bucketization: clamp(ceil(((x+4)/8)*127)-1, 0, 126)
    float t = xv + 4.0f;
    int idx = (int)ceilf(t * 15.875f) - 1;
    idx = min(max(idx, 0), NI - 1);
    float y = fmaf((float)idx, -(8.0f / 127.0f), t);   // y = (x+4) - idx*h
    float2 ab = tAB[idx];
    float2 cd = tCD[idx];
    return fmaf(y, fmaf(y, fmaf(y, cd.y, cd.x), ab.y), ab.x);
}

// ---------- Kernel B: eval + one atomicAdd per block. ----------
__global__ __launch_bounds__(256)
void spline_eval_kernel(const float4* __restrict__ x,
                        const float4* __restrict__ gAB4,   // NM*NI float2 = 508 float4
                        const float4* __restrict__ gCD4,
                        float* __restrict__ out, int n4) {
    __shared__ float2 tabAB[NM * NI];    // 8128 B
    __shared__ float2 tabCD[NM * NI];    // 8128 B
    __shared__ float  wsum[4];
    const int tid = threadIdx.x;

    // coalesced 16 KB table load (L2/L3-resident after block 0)
    for (int t = tid; t < 508; t += 256) {
        ((float4*)tabAB)[t] = gAB4[t];
        ((float4*)tabCD)[t] = gCD4[t];
    }
    __syncthreads();

    const int gid = blockIdx.x * 256 + tid;
    const int S   = GRID * 256;          // stride; S/16384 = 16 (mult of 8) -> f invariant
    const int f = (gid >> 14) & 7;
    const float2* __restrict__ tAB = tabAB + f * NI;
    const float2* __restrict__ tCD = tabCD + f * NI;

    float acc = 0.0f;
    if (gid + (PT - 1) * S < n4) {
        float4 v[PT];
        #pragma unroll
        for (int k = 0; k < PT; ++k) v[k] = x[gid + k * S];   // all 16 loads in flight
        #pragma unroll
        for (int k = 0; k < PT; ++k) {
            acc += eval1(v[k].x, tAB, tCD);
            acc += eval1(v[k].y, tAB, tCD);
            acc += eval1(v[k].z, tAB, tCD);
            acc += eval1(v[k].w, tAB, tCD);
        }
    } else {
        for (int k = 0; k < PT; ++k) {
            int i = gid + k * S;
            if (i < n4) {
                float4 v = x[i];
                acc += eval1(v.x, tAB, tCD); acc += eval1(v.y, tAB, tCD);
                acc += eval1(v.z, tAB, tCD); acc += eval1(v.w, tAB, tCD);
            }
        }
    }

    #pragma unroll
    for (int off = 32; off > 0; off >>= 1) acc += __shfl_down(acc, off);
    int lane = tid & 63;
    int wid  = tid >> 6;
    if (lane == 0) wsum[wid] = acc;
    __syncthreads();
    if (tid == 0) atomicAdd(out, wsum[0] + wsum[1] + wsum[2] + wsum[3]);
}

extern "C" void kernel_launch(void* const* d_in, const int* in_sizes, int n_in,
                              void* d_out, int out_size, void* d_ws, size_t ws_size,
                              hipStream_t stream) {
    const float* x     = (const float*)d_in[0];
    const float* nodal = (const float*)d_in[1];
    float* out = (float*)d_out;

    // d_ws layout: [0, 8128) tabAB (float2[1016]) | [8192, 16320) tabCD
    char* ws = (char*)d_ws;
    float2* gAB = (float2*)(ws);
    float2* gCD = (float2*)(ws + 8192);

    int n4 = in_sizes[0] / 4;   // 4,194,304 = GRID*256*PT exactly

    spline_coeff_kernel<<<1, 256, 0, stream>>>(nodal, gAB, gCD, out);
    spline_eval_kernel<<<GRID, 256, 0, stream>>>((const float4*)x,
                                                 (const float4*)gAB, (const float4*)gCD,
                                                 out, n4);
}

// Round 6
// 102.759 us; speedup vs baseline: 1.0884x; 1.0884x over previous
//
#include <hip/hip_runtime.h>

#define NM 8     // marginals
#define NN 128   // nodes
#define NI 127   // intervals

#define GRID 2048
#define PT 8     // float4 per thread, all loaded up-front for MLP

// Banded rows (half-width 16) of the exact inverse of the [1,4,1] interior
// tridiagonal system (unknowns c[1..126]). Elements decay as (2-sqrt(3))^|i-j|
// ~ 0.268^k, so truncation at +-16 is exact to ~1e-9 relative. Stored
// transposed + padded for coalesced loads: WT[k][i] = Ainv[i][i-16+k] in
// c-index space, i in [0,127]; rows i=0 and i=127 are all-zero => c=0 there.
struct WTab { float v[33 * 128]; };
constexpr WTab make_wt() {
    WTab t{};
    double cp[NI];
    cp[0] = 0.0;
    for (int i = 1; i <= 126; ++i) cp[i] = 1.0 / (4.0 - cp[i - 1]);
    for (int i0 = 1; i0 <= 126; ++i0) {          // solve A w = e_{i0} (symmetric)
        double dp[NN] = {};
        double prev = 0.0;
        for (int i = 1; i <= 126; ++i) {
            double rhs = (i == i0) ? 1.0 : 0.0;
            prev = (rhs - prev) * cp[i];
            dp[i] = prev;
        }
        double w[NN] = {};
        double cn = 0.0;
        for (int i = 126; i >= 1; --i) {
            cn = dp[i] - cp[i] * cn;
            w[i] = cn;
        }
        for (int k = 0; k < 33; ++k) {
            int j = i0 - 16 + k;
            if (j >= 1 && j <= 126) t.v[k * 128 + i0] = (float)w[j];
        }
    }
    return t;
}
__constant__ WTab WT = make_wt();

__device__ __forceinline__ float eval1(float xv,
                                       const float2* __restrict__ tAB,
                                       const float2* __restrict__ tCD) {
    // reference bucketization: clamp(ceil(((x+4)/8)*127)-1, 0, 126)
    float t = xv + 4.0f;
    int idx = (int)ceilf(t * 15.875f) - 1;
    idx = min(max(idx, 0), NI - 1);
    float y = fmaf((float)idx, -(8.0f / 127.0f), t);   // y = (x+4) - idx*h
    float2 ab = tAB[idx];
    float2 cd = tCD[idx];
    return fmaf(y, fmaf(y, fmaf(y, cd.y, cd.x), ab.y), ab.x);
}

// Fused: x-loads issued first (stream under preamble), fully-parallel banded
// coefficient build (no serial chain), then eval; per-block partial -> d_ws.
__global__ __launch_bounds__(256)
void spline_fused_kernel(const float4* __restrict__ x,
                         const float* __restrict__ nodal,
                         float* __restrict__ partials, int n4) {
    __shared__ float  rhsPad[NM][160];   // 5120 B  (16-pad both sides, zeroed)
    __shared__ float  sc[NM][NN];        // 4096 B  c coefficients
    __shared__ float2 tabAB[NM * NI];    // 8128 B
    __shared__ float2 tabCD[NM * NI];    // 8128 B
    __shared__ float  wsum[4];

    const int tid = threadIdx.x;
    const int gid = blockIdx.x * 256 + tid;
    const int S   = GRID * 256;          // k*S/16384 = k*32 -> f invariant

    // --- 1) issue ALL x loads first; they stay in flight during the preamble ---
    float4 v[PT];
    bool full = (gid + (PT - 1) * S < n4);
    if (full) {
        #pragma unroll
        for (int k = 0; k < PT; ++k) v[k] = x[gid + k * S];
    }

    // --- 2) padded rhs from direct nodal reads (1 KB, L1/L3-hot) ---
    const float inv_h2 = (127.0f / 8.0f) * (127.0f / 8.0f);
    #pragma unroll
    for (int u = 0; u < 5; ++u) {        // 8*160 = 1280 = 5*256
        int t = tid + u * 256;
        int f = t / 160, j = t - f * 160;
        int jc = j - 16;                 // c-index
        float val = 0.0f;
        if (jc >= 1 && jc <= 126)
            val = 3.0f * (nodal[f * NN + jc - 1] - 2.0f * nodal[f * NN + jc]
                          + nodal[f * NN + jc + 1]) * inv_h2;
        rhsPad[f][j] = val;
    }
    __syncthreads();

    // --- 3) c = Ainv * rhs via banded weights (fully parallel, 33 FMAs) ---
    {
        const int i = tid & 127;
        const int g = tid >> 7;          // 0 or 1; this thread does f = g,g+2,g+4,g+6
        float a0 = 0.f, a1 = 0.f, a2 = 0.f, a3 = 0.f;
        for (int k = 0; k < 33; ++k) {
            float w = WT.v[k * 128 + i]; // coalesced, L1-resident
            a0 = fmaf(w, rhsPad[g    ][i + k], a0);
            a1 = fmaf(w, rhsPad[g + 2][i + k], a1);
            a2 = fmaf(w, rhsPad[g + 4][i + k], a2);
            a3 = fmaf(w, rhsPad[g + 6][i + k], a3);
        }
        sc[g    ][i] = a0;
        sc[g + 2][i] = a1;
        sc[g + 4][i] = a2;
        sc[g + 6][i] = a3;
    }
    __syncthreads();

    // --- 4) (a,b)/(c,d) tables ---
    const float h = 8.0f / 127.0f, inv_h = 127.0f / 8.0f;
    for (int t = tid; t < NM * NI; t += 256) {
        int f = t / NI, i = t - f * NI;
        float ci  = sc[f][i];
        float ci1 = sc[f][i + 1];
        float a = nodal[f * NN + i];
        float b = (nodal[f * NN + i + 1] - a) * inv_h - h * (2.0f * ci + ci1) * (1.0f / 3.0f);
        float d = (ci1 - ci) * inv_h * (1.0f / 3.0f);
        tabAB[t] = make_float2(a, b);
        tabCD[t] = make_float2(ci, d);
    }
    __syncthreads();

    // --- 5) evaluate (x values already in registers) ---
    const int f = (gid >> 14) & 7;
    const float2* __restrict__ tAB = tabAB + f * NI;
    const float2* __restrict__ tCD = tabCD + f * NI;

    float acc = 0.0f;
    if (full) {
        #pragma unroll
        for (int k = 0; k < PT; ++k) {
            acc += eval1(v[k].x, tAB, tCD);
            acc += eval1(v[k].y, tAB, tCD);
            acc += eval1(v[k].z, tAB, tCD);
            acc += eval1(v[k].w, tAB, tCD);
        }
    } else {
        for (int k = 0; k < PT; ++k) {
            int i = gid + k * S;
            if (i < n4) {
                float4 vv = x[i];
                acc += eval1(vv.x, tAB, tCD); acc += eval1(vv.y, tAB, tCD);
                acc += eval1(vv.z, tAB, tCD); acc += eval1(vv.w, tAB, tCD);
            }
        }
    }

    // --- 6) wave-64 reduce -> LDS -> per-block partial (plain store) ---
    #pragma unroll
    for (int off = 32; off > 0; off >>= 1) acc += __shfl_down(acc, off);
    int lane = tid & 63;
    int wid  = tid >> 6;
    if (lane == 0) wsum[wid] = acc;
    __syncthreads();
    if (tid == 0) partials[blockIdx.x] = wsum[0] + wsum[1] + wsum[2] + wsum[3];
}

// 1 block: sum GRID partials, plain store (no pre-zero of out needed).
__global__ __launch_bounds__(256)
void final_reduce_kernel(const float* __restrict__ partials, float* __restrict__ out) {
    __shared__ float wsum[4];
    float a = 0.0f;
    for (int i = threadIdx.x; i < GRID; i += 256) a += partials[i];
    #pragma unroll
    for (int off = 32; off > 0; off >>= 1) a += __shfl_down(a, off);
    int lane = threadIdx.x & 63, wid = threadIdx.x >> 6;
    if (lane == 0) wsum[wid] = a;
    __syncthreads();
    if (threadIdx.x == 0) out[0] = wsum[0] + wsum[1] + wsum[2] + wsum[3];
}

extern "C" void kernel_launch(void* const* d_in, const int* in_sizes, int n_in,
                              void* d_out, int out_size, void* d_ws, size_t ws_size,
                              hipStream_t stream) {
    const float* x     = (const float*)d_in[0];
    const float* nodal = (const float*)d_in[1];
    float* out      = (float*)d_out;
    float* partials = (float*)d_ws;      // GRID floats

    int n4 = in_sizes[0] / 4;            // 4,194,304 = GRID*256*PT exactly

    spline_fused_kernel<<<GRID, 256, 0, stream>>>((const float4*)x, nodal, partials, n4);
    final_reduce_kernel<<<1, 256, 0, stream>>>(partials, out);
}